// Round 2
// 314.240 us; speedup vs baseline: 1.1476x; 1.1476x over previous
//
#include <hip/hip_runtime.h>
#include <math.h>
#include <stdint.h>

// Problem constants (B,H,W,K,J) = (8,256,256,100,17)
#define HW    65536
#define BATCH 8
#define NJ    17
#define TOPK  100
#define NCH   144   // 8 hm channels + 8*17 hm_hp channels
#define CSTRIDE 16 // counts padded: one counter per 64B cacheline

// d_out float offsets (concatenated outputs, all f32)
#define OFF_HM   0ull
#define OFF_HMHP 20447232ull
#define OFF_DET  30408704ull   // 8*100*40 = 32000 floats

__device__ __forceinline__ float sigmoidf_(float x) {
    return 1.0f / (1.0f + expf(-x));
}

// ---------------------------------------------------------------------------
// Kernel A: elementwise — sigmoid(hm), copy wh, copy hps, copy reg,
// sigmoid(hm_hp), copy hp_offset. One float4 per thread.
// ---------------------------------------------------------------------------
__global__ __launch_bounds__(256) void ew_kernel(
    const float4* __restrict__ in0, const float4* __restrict__ in1,
    const float4* __restrict__ in2, const float4* __restrict__ in3,
    const float4* __restrict__ in4, const float4* __restrict__ in5,
    float4* __restrict__ out)
{
    const int a0 = 131072, a1 = 393216, a2 = 4849664, a3 = 5111808,
              a4 = 7340032, a5 = 7602176;
    int i = blockIdx.x * 256 + threadIdx.x;
    if (i >= a5) return;
    float4 v;
    if (i < a0) {
        v = in0[i];
        v.x = sigmoidf_(v.x); v.y = sigmoidf_(v.y);
        v.z = sigmoidf_(v.z); v.w = sigmoidf_(v.w);
    } else if (i < a1) {
        v = in1[i - a0];
    } else if (i < a2) {
        v = in2[i - a1];
    } else if (i < a3) {
        v = in3[i - a2];
    } else if (i < a4) {
        v = in4[i - a3];
        v.x = sigmoidf_(v.x); v.y = sigmoidf_(v.y);
        v.z = sigmoidf_(v.z); v.w = sigmoidf_(v.w);
    } else {
        v = in5[i - a4];
    }
    out[i] = v;
}

// ---------------------------------------------------------------------------
// NMS'd score at pixel e of a sigmoid map (value if center >= 3x3 max, else 0)
// ---------------------------------------------------------------------------
__device__ __forceinline__ float nms_score(const float* __restrict__ sig, int e) {
    float ce = sig[e];
    int y = e >> 8, x = e & 255;
    bool xm = x > 0, xp = x < 255;
    float m = -INFINITY;
    if (y > 0) {
        if (xm) m = fmaxf(m, sig[e - 257]);
        m = fmaxf(m, sig[e - 256]);
        if (xp) m = fmaxf(m, sig[e - 255]);
    }
    if (xm) m = fmaxf(m, sig[e - 1]);
    if (xp) m = fmaxf(m, sig[e + 1]);
    if (y < 255) {
        if (xm) m = fmaxf(m, sig[e + 255]);
        m = fmaxf(m, sig[e + 256]);
        if (xp) m = fmaxf(m, sig[e + 257]);
    }
    return (ce >= m) ? ce : 0.0f;
}

// ---------------------------------------------------------------------------
// Kernel B: fused NMS + compaction, block-aggregated.
// Each block owns a 4096-pixel slice of one channel. Scores kept in 16
// registers; per-thread positive counts scanned in LDS; ONE global atomic
// per block (counters padded to a cacheline each) fetches the base; threads
// then write their keys at deterministic offsets.
// key = (sortable_float << 16) | (65535 - pix): descending value, ties ->
// lower pix (matches jax.lax.top_k).
// ---------------------------------------------------------------------------
__global__ __launch_bounds__(256) void nms_compact_kernel(
    const float* __restrict__ sig_hm, const float* __restrict__ sig_hmhp,
    unsigned long long* __restrict__ lists, unsigned int* __restrict__ counts,
    int cap)
{
    __shared__ unsigned int sA[256], sB[256];
    __shared__ unsigned int s_base;

    const int c = blockIdx.y;
    const int tid = threadIdx.x;
    const int sliceBase = blockIdx.x * 4096;
    const float* sig = (c < 8) ? (sig_hm + (size_t)c * HW)
                               : (sig_hmhp + (size_t)(c - 8) * HW);

    float v[16];
    unsigned int cnt = 0;
#pragma unroll
    for (int it = 0; it < 16; ++it) {
        int pix = sliceBase + it * 256 + tid;
        v[it] = nms_score(sig, pix);
        cnt += (v[it] > 0.0f) ? 1u : 0u;
    }

    // Block-wide inclusive scan of per-thread counts (Hillis-Steele, LDS).
    sA[tid] = cnt;
    __syncthreads();
    unsigned int* src = sA;
    unsigned int* dst = sB;
#pragma unroll
    for (int off = 1; off < 256; off <<= 1) {
        unsigned int x = src[tid];
        if (tid >= off) x += src[tid - off];
        dst[tid] = x;
        __syncthreads();
        unsigned int* t = src; src = dst; dst = t;
    }
    unsigned int incl = src[tid];
    unsigned int prefix = incl - cnt;          // exclusive prefix
    if (tid == 255)
        s_base = atomicAdd(&counts[c * CSTRIDE], incl);
    __syncthreads();
    unsigned int base = s_base;

    unsigned long long* list = lists + (size_t)c * cap;
    unsigned int pos = base + prefix;
#pragma unroll
    for (int it = 0; it < 16; ++it) {
        if (v[it] > 0.0f) {
            if (pos < (unsigned int)cap) {
                int pix = sliceBase + it * 256 + tid;
                unsigned int su = __float_as_uint(v[it]) | 0x80000000u;
                list[pos] = ((unsigned long long)su << 16) |
                            (unsigned long long)(65535 - pix);
            }
            ++pos;
        }
    }
}

// ---------------------------------------------------------------------------
// Kernel C: top-100 per channel via radix select over the compact candidate
// list (~7300 keys/channel).
//
// v2: the old version's per-pass tid==0 serial scan over 256 LDS chunk sums
// (data-dependent exit -> no pipelining -> ~130cy/iter * 256 * 4 passes
// ~= 55us of pure LDS latency) is replaced by a block-parallel SUFFIX scan;
// the unique thread with S[t] >= krem > S[t+1] resolves its 16 bins from
// registers. Additionally only 2 radix passes (24 key bits) are done: that
// threshold admits top-100 plus prefix-ties (~100-105 keys on this data);
// all admitted keys are collected (256-slot buffer) and bitonic-sorted
// (adaptive 128/256) so the final top-100 + tie-break is still EXACT.
// If prefix-ties ever exceed 256, falls back to passes 3+4 (exact 48-bit
// threshold, exactly 100 distinct keys since pix makes keys unique).
// Fallback 2: if the list overflowed (count > cap), scan the full channel
// recomputing NMS scores.
// Then: hm channels (c<8) -> write det bbox/score/cls + stash inds;
//       hm_hp channels   -> apply hp_offset gather + threshold, stash cands.
// ---------------------------------------------------------------------------
__global__ __launch_bounds__(256) void select_kernel(
    const unsigned long long* __restrict__ lists,
    const unsigned int* __restrict__ counts, int cap,
    const float* __restrict__ sig_hm, const float* __restrict__ sig_hmhp,
    const float* __restrict__ reg, const float* __restrict__ wh,
    const float* __restrict__ hpo,
    float* __restrict__ det, int* __restrict__ ind_hm,
    float* __restrict__ cx, float* __restrict__ cy, float* __restrict__ cs)
{
    __shared__ unsigned int hist[4096];
    __shared__ unsigned int sA[256], sB[256];
    __shared__ unsigned long long keys[256];
    __shared__ unsigned long long s_prefix;
    __shared__ int s_krem;
    __shared__ int s_cnt;

    const int c = blockIdx.x;
    const int tid = threadIdx.x;
    const int total = (int)counts[c * CSTRIDE];
    const bool fb = (total > cap);           // overflow fallback (never on this data)
    const int N = fb ? HW : total;
    const unsigned long long* list = lists + (size_t)c * cap;
    const float* sig = (c < 8) ? (sig_hm + (size_t)c * HW)
                               : (sig_hmhp + (size_t)(c - 8) * HW);

    auto get_key = [&](int i, bool& valid) -> unsigned long long {
        if (!fb) { valid = true; return list[i]; }
        float v = nms_score(sig, i);
        valid = v > 0.0f;
        unsigned int su = __float_as_uint(v) | 0x80000000u;
        return ((unsigned long long)su << 16) | (unsigned long long)(65535 - i);
    };

    if (tid == 0) { s_prefix = 0ULL; s_krem = TOPK; s_cnt = 0; }

    unsigned long long prefix = 0;
    int krem = TOPK;

    // One 12-bit radix pass: histogram -> parallel suffix scan -> refine.
    auto do_pass = [&](int pass) {
        const int shift = 36 - 12 * pass;
        for (int i = tid; i < 4096; i += 256) hist[i] = 0;
        __syncthreads();
        for (int i = tid; i < N; i += 256) {
            bool valid;
            unsigned long long key = get_key(i, valid);
            if (valid && (key >> (shift + 12)) == prefix)
                atomicAdd(&hist[(unsigned int)(key >> shift) & 0xFFFu], 1u);
        }
        __syncthreads();
        unsigned int csum = 0;
#pragma unroll
        for (int i2 = 0; i2 < 16; ++i2) csum += hist[tid * 16 + i2];
        sA[tid] = csum;
        __syncthreads();
        // Suffix inclusive scan: S[t] = sum_{u>=t} chunk[u] (Hillis-Steele).
        unsigned int* src = sA;
        unsigned int* dst = sB;
#pragma unroll
        for (int off = 1; off < 256; off <<= 1) {
            unsigned int x = src[tid];
            if (tid + off < 256) x += src[tid + off];
            dst[tid] = x;
            __syncthreads();
            unsigned int* t = src; src = dst; dst = t;
        }
        unsigned int S = src[tid];
        unsigned int Snext = (tid < 255) ? src[tid + 1] : 0u;
        // Exactly one thread owns the chunk containing the krem-th largest.
        if (S >= (unsigned int)krem && Snext < (unsigned int)krem) {
            unsigned int h[16];
#pragma unroll
            for (int i2 = 0; i2 < 16; ++i2) h[i2] = hist[tid * 16 + i2];
            int cum = (int)Snext;
#pragma unroll
            for (int d = 15; d >= 0; --d) {
                cum += (int)h[d];
                if (cum >= krem) {
                    s_krem = krem - (cum - (int)h[d]);
                    s_prefix = (prefix << 12) | (unsigned long long)(tid * 16 + d);
                    break;
                }
            }
        }
        __syncthreads();
        prefix = s_prefix;
        krem = s_krem;
    };

    // Collect every key whose resolved prefix is >= threshold prefix.
    auto collect = [&](int npass) {
        const int rs = 48 - 12 * npass;
        for (int i = tid; i < N; i += 256) {
            bool valid;
            unsigned long long key = get_key(i, valid);
            if (valid && (key >> rs) >= prefix) {
                int pos = atomicAdd(&s_cnt, 1);
                if (pos < 256) keys[pos] = key;
            }
        }
        __syncthreads();
    };

    do_pass(0);
    do_pass(1);
    collect(2);
    int cnt = s_cnt;

    if (cnt > 256) {
        // Pathological tie storm at 24-bit granularity: resolve exactly.
        do_pass(2);
        do_pass(3);
        if (tid == 0) s_cnt = 0;
        __syncthreads();
        collect(4);           // keys are unique -> exactly TOPK collected
        cnt = s_cnt;
        if (cnt > 256) cnt = 256;
    }

    // Zero-fill tail, bitonic sort descending (adaptive width).
    const int nsort = (cnt <= 128) ? 128 : 256;
    for (int i = tid; i < nsort; i += 256)
        if (i >= cnt) keys[i] = 0ULL;

    for (int ksz = 2; ksz <= nsort; ksz <<= 1) {
        for (int jj = ksz >> 1; jj > 0; jj >>= 1) {
            __syncthreads();
            if (tid < nsort) {
                int ixj = tid ^ jj;
                if (ixj > tid) {
                    unsigned long long a = keys[tid], b2 = keys[ixj];
                    bool up = ((tid & ksz) == 0);
                    if (up ? (a < b2) : (a > b2)) {
                        keys[tid] = b2;
                        keys[ixj] = a;
                    }
                }
            }
        }
    }
    __syncthreads();

    if (tid < TOPK) {
        unsigned long long key = keys[tid];
        float val = __uint_as_float((unsigned int)(key >> 16) & 0x7FFFFFFFu);
        int pix = 65535 - (int)(key & 0xFFFFull);
        if (c < 8) {
            int b = c;
            ind_hm[b * TOPK + tid] = pix;
            float xs0 = (float)(pix & 255), ys0 = (float)(pix >> 8);
            float r0 = reg[((size_t)b * 2 + 0) * HW + pix];
            float r1 = reg[((size_t)b * 2 + 1) * HW + pix];
            float w0 = wh[((size_t)b * 2 + 0) * HW + pix];
            float w1 = wh[((size_t)b * 2 + 1) * HW + pix];
            float xs = xs0 + r0, ys = ys0 + r1;
            float* row = det + ((size_t)b * TOPK + tid) * 40;
            row[0] = xs - w0 * 0.5f;
            row[1] = ys - w1 * 0.5f;
            row[2] = xs + w0 * 0.5f;
            row[3] = ys + w1 * 0.5f;
            row[4] = val;
            row[39] = 0.0f;   // cls (C=1 -> always 0)
        } else {
            int cc = c - 8, b = cc / NJ, j = cc % NJ;
            float xs = (float)(pix & 255), ys = (float)(pix >> 8);
            float o0 = hpo[((size_t)b * 2 + 0) * HW + pix];
            float o1 = hpo[((size_t)b * 2 + 1) * HW + pix];
            bool m = val > 0.1f;
            int idx = (b * NJ + j) * TOPK + tid;
            cs[idx] = m ? val : -1.0f;
            cx[idx] = m ? (xs + o0) : -10000.0f;
            cy[idx] = m ? (ys + o1) : -10000.0f;
        }
    }
}

// ---------------------------------------------------------------------------
// Kernel D: per (b,j) block — for each detection k: gather kp regression,
// nearest hm_hp candidate (strict-< keeps first index, matching argmin),
// bad-check against bbox, write kps to detection rows.
// ---------------------------------------------------------------------------
__global__ __launch_bounds__(128) void assign_kernel(
    const float* __restrict__ hps, const int* __restrict__ ind_hm,
    const float* __restrict__ cx, const float* __restrict__ cy,
    const float* __restrict__ cs, float* __restrict__ det)
{
    __shared__ float sx[TOPK], sy[TOPK], ss[TOPK];
    __shared__ float sl[TOPK], st[TOPK], sr[TOPK], sb[TOPK];
    __shared__ float x0[TOPK], y0[TOPK];
    __shared__ int sind[TOPK];

    int b = blockIdx.x / NJ, j = blockIdx.x % NJ;
    int k = threadIdx.x;
    if (k < TOPK) {
        int base = (b * NJ + j) * TOPK + k;
        sx[k] = cx[base]; sy[k] = cy[base]; ss[k] = cs[base];
        const float* row = det + ((size_t)b * TOPK + k) * 40;
        sl[k] = row[0]; st[k] = row[1]; sr[k] = row[2]; sb[k] = row[3];
        int ind = ind_hm[b * TOPK + k];
        sind[k] = ind;
        x0[k] = (float)(ind & 255);
        y0[k] = (float)(ind >> 8);
    }
    __syncthreads();
    if (k < TOPK) {
        int ind = sind[k];
        float kx = hps[((size_t)b * 34 + 2 * j + 0) * HW + ind] + x0[k];
        float ky = hps[((size_t)b * 34 + 2 * j + 1) * HW + ind] + y0[k];
        float best = INFINITY;
        int bi = 0;
        for (int cand = 0; cand < TOPK; ++cand) {
            float dx = kx - sx[cand], dy = ky - sy[cand];
            float d = sqrtf(dx * dx + dy * dy);
            if (d < best) { best = d; bi = cand; }
        }
        float hx = sx[bi], hy = sy[bi], hs = ss[bi];
        float w = sr[k] - sl[k], h = sb[k] - st[k];
        bool bad = (hx < sl[k]) || (hx > sr[k]) || (hy < st[k]) || (hy > sb[k]) ||
                   (hs < 0.1f) || (best > fmaxf(h, w) * 0.3f);
        float ox = bad ? kx : hx;
        float oy = bad ? ky : hy;
        float* orow = det + ((size_t)b * TOPK + k) * 40;
        orow[5 + 2 * j] = ox;
        orow[6 + 2 * j] = oy;
    }
}

// ---------------------------------------------------------------------------
extern "C" void kernel_launch(void* const* d_in, const int* in_sizes, int n_in,
                              void* d_out, int out_size, void* d_ws, size_t ws_size,
                              hipStream_t stream) {
    const float* hm    = (const float*)d_in[0];
    const float* wh    = (const float*)d_in[1];
    const float* hps   = (const float*)d_in[2];
    const float* reg   = (const float*)d_in[3];
    const float* hm_hp = (const float*)d_in[4];
    const float* hpo   = (const float*)d_in[5];
    float* out = (float*)d_out;

    // Workspace layout:
    //   counts : u32 [144*16]     @ 0       (padded, 1 counter / cacheline)
    //   ind_hm : int [800]        @ 16384
    //   cx     : f32 [8*17*100]   @ 32768
    //   cy     : f32 [8*17*100]   @ 98304
    //   cs     : f32 [8*17*100]   @ 163840
    //   lists  : u64 [144*cap]    @ 262144
    char* ws = (char*)d_ws;
    unsigned int* counts = (unsigned int*)ws;
    int*   ind_hm = (int*)(ws + 16384);
    float* cx = (float*)(ws + 32768);
    float* cy = (float*)(ws + 98304);
    float* cs = (float*)(ws + 163840);
    unsigned long long* lists = (unsigned long long*)(ws + 262144);
    long long avail = (long long)ws_size - 262144;
    int cap = 0;
    if (avail > 0) {
        long long c = avail / ((long long)NCH * 8);
        cap = (c > 16384) ? 16384 : (int)c;
    }

    hipMemsetAsync(counts, 0, NCH * CSTRIDE * sizeof(unsigned int), stream);

    ew_kernel<<<29696, 256, 0, stream>>>(
        (const float4*)hm, (const float4*)wh, (const float4*)hps,
        (const float4*)reg, (const float4*)hm_hp, (const float4*)hpo,
        (float4*)out);

    const float* sig_hm   = out + OFF_HM;
    const float* sig_hmhp = out + OFF_HMHP;
    float* det = out + OFF_DET;

    nms_compact_kernel<<<dim3(16, NCH), 256, 0, stream>>>(
        sig_hm, sig_hmhp, lists, counts, cap);

    select_kernel<<<NCH, 256, 0, stream>>>(
        lists, counts, cap, sig_hm, sig_hmhp, reg, wh, hpo,
        det, ind_hm, cx, cy, cs);

    assign_kernel<<<BATCH * NJ, 128, 0, stream>>>(hps, ind_hm, cx, cy, cs, det);
}

// Round 3
// 250.286 us; speedup vs baseline: 1.4408x; 1.2555x over previous
//
#include <hip/hip_runtime.h>
#include <math.h>
#include <stdint.h>

// Problem constants (B,H,W,K,J) = (8,256,256,100,17)
#define HW    65536
#define BATCH 8
#define NJ    17
#define TOPK  100
#define NCH   144   // 8 hm channels + 8*17 hm_hp channels
#define CSTRIDE 16 // counts padded: one counter per 64B cacheline

// d_out float offsets (concatenated outputs, all f32)
#define OFF_HM   0ull
#define OFF_HMHP 20447232ull
#define OFF_DET  30408704ull   // 8*100*40 = 32000 floats

// Fused kernel geometry
#define NMS_BLOCKS  (NCH * 16)   // 2304: each block = 16 rows of one channel
#define COPY_F4     5242880      // wh+hps+reg+hpo in float4 units
#define COPY_BLOCKS (COPY_F4 / 256)  // 20480

// Candidate pre-threshold = sigmoid(2.0). Top-100 of ~7300 NMS survivors on
// N(0,1) logits sits at sig~0.90, and ~1200 candidates/channel exceed this
// threshold. EXACT: if a channel stores >= TOPK keys above threshold, its
// top-100 equals the unthresholded top-100; otherwise select_kernel's fb
// path rescans the full channel with no threshold.
#define TS 0.8807970779778824f

__device__ __forceinline__ float sigmoidf_(float x) {
    return 1.0f / (1.0f + expf(-x));
}

// ---------------------------------------------------------------------------
// Fused kernel: two roles by blockIdx.
//  - blocks [0, NMS_BLOCKS): channel c = bx>>4, slice = bx&15 (16 rows).
//    Load raw logits (+halo rows), sigmoid once, stage in LDS, write the
//    sigmoid map to out, 3x3-NMS from LDS, compact candidates >= TS into
//    per-channel lists (block scan + 1 global atomic), key =
//    (sortable_float<<16) | (65535-pix)  -> descending value, ties = lower
//    pix (matches jax.lax.top_k).
//  - blocks [NMS_BLOCKS, +COPY_BLOCKS): float4 copies of wh/hps/reg/hpo.
// Sigmoid values are computed with the same formula as before -> candidate
// sets identical to the previous two-kernel version.
// ---------------------------------------------------------------------------
__global__ __launch_bounds__(256) void fused_kernel(
    const float*  __restrict__ hm,  const float4* __restrict__ wh4,
    const float4* __restrict__ hps4, const float4* __restrict__ reg4,
    const float*  __restrict__ hm_hp, const float4* __restrict__ hpo4,
    float* __restrict__ out,
    unsigned long long* __restrict__ lists, unsigned int* __restrict__ counts,
    int cap)
{
    const int tid = threadIdx.x;
    const int bx  = blockIdx.x;

    if (bx >= NMS_BLOCKS) {
        // ---- copy role ----
        int j = (bx - NMS_BLOCKS) * 256 + tid;     // < COPY_F4 exactly
        float4* o4 = (float4*)out;
        const int b0 = 262144, b1 = 4718592, b2 = 4980736;
        float4 v; int dst;
        if (j < b0)      { v = wh4[j];        dst = 131072  + j; }
        else if (j < b1) { v = hps4[j - b0];  dst = 393216  + (j - b0); }
        else if (j < b2) { v = reg4[j - b1];  dst = 4849664 + (j - b1); }
        else             { v = hpo4[j - b2];  dst = 7340032 + (j - b2); }
        o4[dst] = v;
        return;
    }

    // ---- NMS role ----
    __shared__ float sig[18 * 256];
    __shared__ unsigned int sA[256], sB[256];
    __shared__ unsigned int s_base;

    const int c = bx >> 4, slice = bx & 15;
    const float* src = (c < 8) ? (hm    + (size_t)c * HW)
                               : (hm_hp + (size_t)(c - 8) * HW);
    float* dst = (c < 8) ? (out + (size_t)c * HW)
                         : (out + OFF_HMHP + (size_t)(c - 8) * HW);
    const int g0 = slice * 16;

    // Load 16 interior rows + 2 halo rows, sigmoid once, stage + write out.
    for (int r = -1; r <= 16; ++r) {
        int g = g0 + r;
        float v = -INFINITY;                        // reduce_window pad value
        if (g >= 0 && g <= 255) v = sigmoidf_(src[g * 256 + tid]);
        sig[(r + 1) * 256 + tid] = v;
        if (r >= 0 && r < 16) dst[g * 256 + tid] = v;
    }
    __syncthreads();

    // 3x3 NMS from LDS (row stride 256 floats -> 2-way bank alias, free).
    float v[16];
    unsigned int cnt = 0;
    const bool xm = tid > 0, xp = tid < 255;
#pragma unroll
    for (int it = 0; it < 16; ++it) {
        int bse = it * 256 + tid;                   // row above center
        float ce = sig[bse + 256];
        float m = -INFINITY;
        if (xm) m = fmaxf(m, sig[bse - 1]);
        m = fmaxf(m, sig[bse]);
        if (xp) m = fmaxf(m, sig[bse + 1]);
        if (xm) m = fmaxf(m, sig[bse + 255]);
        if (xp) m = fmaxf(m, sig[bse + 257]);
        if (xm) m = fmaxf(m, sig[bse + 511]);
        m = fmaxf(m, sig[bse + 512]);
        if (xp) m = fmaxf(m, sig[bse + 513]);
        float val = (ce >= m && ce >= TS) ? ce : 0.0f;
        v[it] = val;
        cnt += (val > 0.0f) ? 1u : 0u;
    }

    // Block-wide inclusive scan of per-thread counts (Hillis-Steele, LDS).
    sA[tid] = cnt;
    __syncthreads();
    unsigned int* psrc = sA;
    unsigned int* pdst = sB;
#pragma unroll
    for (int off = 1; off < 256; off <<= 1) {
        unsigned int x = psrc[tid];
        if (tid >= off) x += psrc[tid - off];
        pdst[tid] = x;
        __syncthreads();
        unsigned int* t = psrc; psrc = pdst; pdst = t;
    }
    unsigned int incl = psrc[tid];
    unsigned int prefix = incl - cnt;          // exclusive prefix
    if (tid == 255)
        s_base = atomicAdd(&counts[c * CSTRIDE], incl);
    __syncthreads();
    unsigned int base = s_base;

    unsigned long long* list = lists + (size_t)c * cap;
    unsigned int pos = base + prefix;
    const int sliceBase = slice * 4096;
#pragma unroll
    for (int it = 0; it < 16; ++it) {
        if (v[it] > 0.0f) {
            if (pos < (unsigned int)cap) {
                int pix = sliceBase + it * 256 + tid;
                unsigned int su = __float_as_uint(v[it]) | 0x80000000u;
                list[pos] = ((unsigned long long)su << 16) |
                            (unsigned long long)(65535 - pix);
            }
            ++pos;
        }
    }
}

// ---------------------------------------------------------------------------
// NMS'd score at pixel e of a sigmoid map (value if center >= 3x3 max, else 0)
// Used only by select_kernel's fallback full-channel rescan.
// ---------------------------------------------------------------------------
__device__ __forceinline__ float nms_score(const float* __restrict__ sig, int e) {
    float ce = sig[e];
    int y = e >> 8, x = e & 255;
    bool xm = x > 0, xp = x < 255;
    float m = -INFINITY;
    if (y > 0) {
        if (xm) m = fmaxf(m, sig[e - 257]);
        m = fmaxf(m, sig[e - 256]);
        if (xp) m = fmaxf(m, sig[e - 255]);
    }
    if (xm) m = fmaxf(m, sig[e - 1]);
    if (xp) m = fmaxf(m, sig[e + 1]);
    if (y < 255) {
        if (xm) m = fmaxf(m, sig[e + 255]);
        m = fmaxf(m, sig[e + 256]);
        if (xp) m = fmaxf(m, sig[e + 257]);
    }
    return (ce >= m) ? ce : 0.0f;
}

// ---------------------------------------------------------------------------
// Kernel C: top-100 per channel via radix select over the compact candidate
// list (~1200 keys/channel after the TS pre-threshold).
// Parallel suffix-scan bucket search (no serial tid==0 loop); 2 radix passes
// (24 bits) + over-collect (256 slots) + adaptive bitonic = exact top-100
// incl. tie-break. Fallbacks: tie-storm -> passes 3+4; list overflow OR
// fewer than TOPK thresholded candidates -> full-channel rescan (fb).
// Then: hm channels (c<8) -> write det bbox/score/cls + stash inds;
//       hm_hp channels   -> apply hp_offset gather + threshold, stash cands.
// ---------------------------------------------------------------------------
__global__ __launch_bounds__(256) void select_kernel(
    const unsigned long long* __restrict__ lists,
    const unsigned int* __restrict__ counts, int cap,
    const float* __restrict__ sig_hm, const float* __restrict__ sig_hmhp,
    const float* __restrict__ reg, const float* __restrict__ wh,
    const float* __restrict__ hpo,
    float* __restrict__ det, int* __restrict__ ind_hm,
    float* __restrict__ cx, float* __restrict__ cy, float* __restrict__ cs)
{
    __shared__ unsigned int hist[4096];
    __shared__ unsigned int sA[256], sB[256];
    __shared__ unsigned long long keys[256];
    __shared__ unsigned long long s_prefix;
    __shared__ int s_krem;
    __shared__ int s_cnt;

    const int c = blockIdx.x;
    const int tid = threadIdx.x;
    const int total = (int)counts[c * CSTRIDE];
    // Fallback: list overflow, or pre-threshold kept fewer than TOPK keys.
    const bool fb = (total > cap) || (total < TOPK);
    const int N = fb ? HW : total;
    const unsigned long long* list = lists + (size_t)c * cap;
    const float* sig = (c < 8) ? (sig_hm + (size_t)c * HW)
                               : (sig_hmhp + (size_t)(c - 8) * HW);

    auto get_key = [&](int i, bool& valid) -> unsigned long long {
        if (!fb) { valid = true; return list[i]; }
        float v = nms_score(sig, i);
        valid = v > 0.0f;
        unsigned int su = __float_as_uint(v) | 0x80000000u;
        return ((unsigned long long)su << 16) | (unsigned long long)(65535 - i);
    };

    if (tid == 0) { s_prefix = 0ULL; s_krem = TOPK; s_cnt = 0; }

    unsigned long long prefix = 0;
    int krem = TOPK;

    // One 12-bit radix pass: histogram -> parallel suffix scan -> refine.
    auto do_pass = [&](int pass) {
        const int shift = 36 - 12 * pass;
        for (int i = tid; i < 4096; i += 256) hist[i] = 0;
        __syncthreads();
        for (int i = tid; i < N; i += 256) {
            bool valid;
            unsigned long long key = get_key(i, valid);
            if (valid && (key >> (shift + 12)) == prefix)
                atomicAdd(&hist[(unsigned int)(key >> shift) & 0xFFFu], 1u);
        }
        __syncthreads();
        unsigned int csum = 0;
#pragma unroll
        for (int i2 = 0; i2 < 16; ++i2) csum += hist[tid * 16 + i2];
        sA[tid] = csum;
        __syncthreads();
        // Suffix inclusive scan: S[t] = sum_{u>=t} chunk[u] (Hillis-Steele).
        unsigned int* src = sA;
        unsigned int* dst = sB;
#pragma unroll
        for (int off = 1; off < 256; off <<= 1) {
            unsigned int x = src[tid];
            if (tid + off < 256) x += src[tid + off];
            dst[tid] = x;
            __syncthreads();
            unsigned int* t = src; src = dst; dst = t;
        }
        unsigned int S = src[tid];
        unsigned int Snext = (tid < 255) ? src[tid + 1] : 0u;
        // Exactly one thread owns the chunk containing the krem-th largest.
        if (S >= (unsigned int)krem && Snext < (unsigned int)krem) {
            unsigned int h[16];
#pragma unroll
            for (int i2 = 0; i2 < 16; ++i2) h[i2] = hist[tid * 16 + i2];
            int cum = (int)Snext;
#pragma unroll
            for (int d = 15; d >= 0; --d) {
                cum += (int)h[d];
                if (cum >= krem) {
                    s_krem = krem - (cum - (int)h[d]);
                    s_prefix = (prefix << 12) | (unsigned long long)(tid * 16 + d);
                    break;
                }
            }
        }
        __syncthreads();
        prefix = s_prefix;
        krem = s_krem;
    };

    // Collect every key whose resolved prefix is >= threshold prefix.
    auto collect = [&](int npass) {
        const int rs = 48 - 12 * npass;
        for (int i = tid; i < N; i += 256) {
            bool valid;
            unsigned long long key = get_key(i, valid);
            if (valid && (key >> rs) >= prefix) {
                int pos = atomicAdd(&s_cnt, 1);
                if (pos < 256) keys[pos] = key;
            }
        }
        __syncthreads();
    };

    do_pass(0);
    do_pass(1);
    collect(2);
    int cnt = s_cnt;

    if (cnt > 256) {
        // Pathological tie storm at 24-bit granularity: resolve exactly.
        do_pass(2);
        do_pass(3);
        if (tid == 0) s_cnt = 0;
        __syncthreads();
        collect(4);           // keys are unique -> exactly TOPK collected
        cnt = s_cnt;
        if (cnt > 256) cnt = 256;
    }

    // Zero-fill tail, bitonic sort descending (adaptive width).
    const int nsort = (cnt <= 128) ? 128 : 256;
    for (int i = tid; i < nsort; i += 256)
        if (i >= cnt) keys[i] = 0ULL;

    for (int ksz = 2; ksz <= nsort; ksz <<= 1) {
        for (int jj = ksz >> 1; jj > 0; jj >>= 1) {
            __syncthreads();
            if (tid < nsort) {
                int ixj = tid ^ jj;
                if (ixj > tid) {
                    unsigned long long a = keys[tid], b2 = keys[ixj];
                    bool up = ((tid & ksz) == 0);
                    if (up ? (a < b2) : (a > b2)) {
                        keys[tid] = b2;
                        keys[ixj] = a;
                    }
                }
            }
        }
    }
    __syncthreads();

    if (tid < TOPK) {
        unsigned long long key = keys[tid];
        float val = __uint_as_float((unsigned int)(key >> 16) & 0x7FFFFFFFu);
        int pix = 65535 - (int)(key & 0xFFFFull);
        if (c < 8) {
            int b = c;
            ind_hm[b * TOPK + tid] = pix;
            float xs0 = (float)(pix & 255), ys0 = (float)(pix >> 8);
            float r0 = reg[((size_t)b * 2 + 0) * HW + pix];
            float r1 = reg[((size_t)b * 2 + 1) * HW + pix];
            float w0 = wh[((size_t)b * 2 + 0) * HW + pix];
            float w1 = wh[((size_t)b * 2 + 1) * HW + pix];
            float xs = xs0 + r0, ys = ys0 + r1;
            float* row = det + ((size_t)b * TOPK + tid) * 40;
            row[0] = xs - w0 * 0.5f;
            row[1] = ys - w1 * 0.5f;
            row[2] = xs + w0 * 0.5f;
            row[3] = ys + w1 * 0.5f;
            row[4] = val;
            row[39] = 0.0f;   // cls (C=1 -> always 0)
        } else {
            int cc = c - 8, b = cc / NJ, j = cc % NJ;
            float xs = (float)(pix & 255), ys = (float)(pix >> 8);
            float o0 = hpo[((size_t)b * 2 + 0) * HW + pix];
            float o1 = hpo[((size_t)b * 2 + 1) * HW + pix];
            bool m = val > 0.1f;
            int idx = (b * NJ + j) * TOPK + tid;
            cs[idx] = m ? val : -1.0f;
            cx[idx] = m ? (xs + o0) : -10000.0f;
            cy[idx] = m ? (ys + o1) : -10000.0f;
        }
    }
}

// ---------------------------------------------------------------------------
// Kernel D: per (b,j) block — for each detection k: gather kp regression,
// nearest hm_hp candidate (strict-< keeps first index, matching argmin),
// bad-check against bbox, write kps to detection rows.
// ---------------------------------------------------------------------------
__global__ __launch_bounds__(128) void assign_kernel(
    const float* __restrict__ hps, const int* __restrict__ ind_hm,
    const float* __restrict__ cx, const float* __restrict__ cy,
    const float* __restrict__ cs, float* __restrict__ det)
{
    __shared__ float sx[TOPK], sy[TOPK], ss[TOPK];
    __shared__ float sl[TOPK], st[TOPK], sr[TOPK], sb[TOPK];
    __shared__ float x0[TOPK], y0[TOPK];
    __shared__ int sind[TOPK];

    int b = blockIdx.x / NJ, j = blockIdx.x % NJ;
    int k = threadIdx.x;
    if (k < TOPK) {
        int base = (b * NJ + j) * TOPK + k;
        sx[k] = cx[base]; sy[k] = cy[base]; ss[k] = cs[base];
        const float* row = det + ((size_t)b * TOPK + k) * 40;
        sl[k] = row[0]; st[k] = row[1]; sr[k] = row[2]; sb[k] = row[3];
        int ind = ind_hm[b * TOPK + k];
        sind[k] = ind;
        x0[k] = (float)(ind & 255);
        y0[k] = (float)(ind >> 8);
    }
    __syncthreads();
    if (k < TOPK) {
        int ind = sind[k];
        float kx = hps[((size_t)b * 34 + 2 * j + 0) * HW + ind] + x0[k];
        float ky = hps[((size_t)b * 34 + 2 * j + 1) * HW + ind] + y0[k];
        float best = INFINITY;
        int bi = 0;
        for (int cand = 0; cand < TOPK; ++cand) {
            float dx = kx - sx[cand], dy = ky - sy[cand];
            float d = sqrtf(dx * dx + dy * dy);
            if (d < best) { best = d; bi = cand; }
        }
        float hx = sx[bi], hy = sy[bi], hs = ss[bi];
        float w = sr[k] - sl[k], h = sb[k] - st[k];
        bool bad = (hx < sl[k]) || (hx > sr[k]) || (hy < st[k]) || (hy > sb[k]) ||
                   (hs < 0.1f) || (best > fmaxf(h, w) * 0.3f);
        float ox = bad ? kx : hx;
        float oy = bad ? ky : hy;
        float* orow = det + ((size_t)b * TOPK + k) * 40;
        orow[5 + 2 * j] = ox;
        orow[6 + 2 * j] = oy;
    }
}

// ---------------------------------------------------------------------------
extern "C" void kernel_launch(void* const* d_in, const int* in_sizes, int n_in,
                              void* d_out, int out_size, void* d_ws, size_t ws_size,
                              hipStream_t stream) {
    const float* hm    = (const float*)d_in[0];
    const float* wh    = (const float*)d_in[1];
    const float* hps   = (const float*)d_in[2];
    const float* reg   = (const float*)d_in[3];
    const float* hm_hp = (const float*)d_in[4];
    const float* hpo   = (const float*)d_in[5];
    float* out = (float*)d_out;

    // Workspace layout:
    //   counts : u32 [144*16]     @ 0       (padded, 1 counter / cacheline)
    //   ind_hm : int [800]        @ 16384
    //   cx     : f32 [8*17*100]   @ 32768
    //   cy     : f32 [8*17*100]   @ 98304
    //   cs     : f32 [8*17*100]   @ 163840
    //   lists  : u64 [144*cap]    @ 262144
    char* ws = (char*)d_ws;
    unsigned int* counts = (unsigned int*)ws;
    int*   ind_hm = (int*)(ws + 16384);
    float* cx = (float*)(ws + 32768);
    float* cy = (float*)(ws + 98304);
    float* cs = (float*)(ws + 163840);
    unsigned long long* lists = (unsigned long long*)(ws + 262144);
    long long avail = (long long)ws_size - 262144;
    int cap = 0;
    if (avail > 0) {
        long long c = avail / ((long long)NCH * 8);
        cap = (c > 16384) ? 16384 : (int)c;
    }

    hipMemsetAsync(counts, 0, NCH * CSTRIDE * sizeof(unsigned int), stream);

    const float* sig_hm   = out + OFF_HM;
    const float* sig_hmhp = out + OFF_HMHP;
    float* det = out + OFF_DET;

    fused_kernel<<<NMS_BLOCKS + COPY_BLOCKS, 256, 0, stream>>>(
        hm, (const float4*)wh, (const float4*)hps, (const float4*)reg,
        hm_hp, (const float4*)hpo, out, lists, counts, cap);

    select_kernel<<<NCH, 256, 0, stream>>>(
        lists, counts, cap, sig_hm, sig_hmhp, reg, wh, hpo,
        det, ind_hm, cx, cy, cs);

    assign_kernel<<<BATCH * NJ, 128, 0, stream>>>(hps, ind_hm, cx, cy, cs, det);
}